// Round 4
// baseline (228.391 us; speedup 1.0000x reference)
//
#include <hip/hip_runtime.h>

#define IMG_H 512
#define IMG_W 512
#define VIEW_TAN_F 0.57735026918962576451f  // tan(30 deg)
#define NEARZ 0.1f
#define BIGF 1e10f

#define TILE 16
#define NTX (IMG_W / TILE)      // 32 tiles per row
#define NTILES (NTX * NTX)      // 1024 tiles
#define RSPLITS 8               // blocks sharing one tile's face list (strided)
#define RCHUNK 256              // list entries staged to LDS per round

// Per-face data: 3 x float4 = {A0,B0,C0,A1},{B1,C1,A2,B2},{C2,Az,Bz,Cz}
// Edge coefficients premultiplied by sign(area): inside <=> w0,w1,w2 >= 0.
// z = Az*x + Bz*y + Cz (affine; division by area folded into coefficients).

// Fused: per-face setup + zbuf/out init + face-parallel tile binning.
// Binning = bbox tile range + the validated dilated-edge test; list order is
// nondeterministic (atomicAdd) but the u64 atomicMin merge is order-invariant.
__global__ void prep_bin(const float* __restrict__ verts,
                         const int* __restrict__ faces,
                         const float* __restrict__ tex,
                         const float* __restrict__ campos,
                         const float* __restrict__ camup,
                         float4* __restrict__ fd,
                         float* __restrict__ cols,
                         unsigned long long* __restrict__ zbuf,
                         int* __restrict__ counts,
                         int* __restrict__ lists,
                         float* __restrict__ out,
                         int F)
{
    int gid = blockIdx.x * blockDim.x + threadIdx.x;

    if (gid == 0 && out) out[0] = 0.0f;      // d_out poisoned 0xAA each call

    if (zbuf) {
        const int P = IMG_H * IMG_W;
        for (int i = gid; i < P; i += gridDim.x * blockDim.x)
            zbuf[i] = ~0ull;
    }

    int f = gid;
    if (f >= F) return;

    float ex = campos[0], ey = campos[1], ez = campos[2];
    float ux = camup[0], uy = camup[1], uz = camup[2];
    float zxv = -ex, zyv = -ey, zzv = -ez;
    float inv = 1.0f / (sqrtf(zxv*zxv + zyv*zyv + zzv*zzv) + 1e-12f);
    zxv *= inv; zyv *= inv; zzv *= inv;
    inv = 1.0f / (sqrtf(ux*ux + uy*uy + uz*uz) + 1e-12f);
    ux *= inv; uy *= inv; uz *= inv;
    float xxv = uy*zzv - uz*zyv;
    float xyv = uz*zxv - ux*zzv;
    float xzv = ux*zyv - uy*zxv;
    inv = 1.0f / (sqrtf(xxv*xxv + xyv*xyv + xzv*xzv) + 1e-12f);
    xxv *= inv; xyv *= inv; xzv *= inv;
    float yxv = zyv*xzv - zzv*xyv;
    float yyv = zzv*xxv - zxv*xzv;
    float yzv = zxv*xyv - zyv*xxv;

    float px_[3], py_[3], pz_[3];
    #pragma unroll
    for (int k = 0; k < 3; ++k) {
        int vi = faces[f*3 + k];
        float vx = verts[vi*3+0] - ex;
        float vy = verts[vi*3+1] - ey;
        float vz = verts[vi*3+2] - ez;
        float cx = xxv*vx + xyv*vy + xzv*vz;
        float cy = yxv*vx + yyv*vy + yzv*vz;
        float cz = zxv*vx + zyv*vy + zzv*vz;
        float denom = cz * VIEW_TAN_F + 1e-12f;
        px_[k] = cx / denom;
        py_[k] = cy / denom;
        pz_[k] = cz;
    }
    float x0 = px_[0], y0 = py_[0];
    float x1 = px_[1], y1 = py_[1];
    float x2 = px_[2], y2 = py_[2];
    float area = (x1-x0)*(y2-y0) - (y1-y0)*(x2-x0);
    bool valid = fabsf(area) > 1e-8f;
    float safe = valid ? area : 1.0f;
    float s = (area > 0.0f) ? 1.0f : -1.0f;

    float A0 = -(y2-y1), B0 = (x2-x1), C0 = (y2-y1)*x1 - (x2-x1)*y1;
    float A1 = -(y0-y2), B1 = (x0-x2), C1 = (y0-y2)*x2 - (x0-x2)*y2;
    float A2 = -(y1-y0), B2 = (x1-x0), C2 = (y1-y0)*x0 - (x1-x0)*y0;

    float invs = 1.0f / safe;
    float Az = (A0*pz_[0] + A1*pz_[1] + A2*pz_[2]) * invs;
    float Bz = (B0*pz_[0] + B1*pz_[1] + B2*pz_[2]) * invs;
    float Cz = (C0*pz_[0] + C1*pz_[1] + C2*pz_[2]) * invs;

    A0 *= s; B0 *= s; C0 *= s;
    A1 *= s; B1 *= s; C1 *= s;
    A2 *= s; B2 *= s; C2 *= s;

    if (!valid) {
        A0 = B0 = A1 = B1 = A2 = B2 = 0.0f;
        C0 = C1 = C2 = -1.0f;
        Az = Bz = 0.0f; Cz = 0.0f;
    }

    fd[f*3+0] = make_float4(A0, B0, C0, A1);
    fd[f*3+1] = make_float4(B1, C1, A2, B2);
    fd[f*3+2] = make_float4(C2, Az, Bz, Cz);

    float c0 = 0.0f, c1 = 0.0f, c2 = 0.0f;
    #pragma unroll
    for (int t = 0; t < 8; ++t) {
        c0 += tex[f*24 + t*3 + 0];
        c1 += tex[f*24 + t*3 + 1];
        c2 += tex[f*24 + t*3 + 2];
    }
    cols[f*3+0] = c0 * 0.125f;
    cols[f*3+1] = c1 * 0.125f;
    cols[f*3+2] = c2 * 0.125f;

    if (!valid || !lists) return;

    // ---- face-parallel binning over bbox tile range ----
    float sxmin = fminf(fminf(x0, x1), x2);
    float sxmax = fmaxf(fmaxf(x0, x1), x2);
    float symin = fminf(fminf(y0, y1), y2);
    float symax = fmaxf(fmaxf(y0, y1), y2);

    // pixel center: x_c=(c+0.5)/256-1, y_c=1-(r+0.5)/256; +-1px fp slack
    int c0p = (int)ceilf ((sxmin + 1.0f) * 256.0f - 0.5f) - 1;
    int c1p = (int)floorf((sxmax + 1.0f) * 256.0f - 0.5f) + 1;
    int r0p = (int)ceilf ((1.0f - symax) * 256.0f - 0.5f) - 1;
    int r1p = (int)floorf((1.0f - symin) * 256.0f - 0.5f) + 1;
    c0p = max(c0p, 0); c1p = min(c1p, IMG_W - 1);
    r0p = max(r0p, 0); r1p = min(r1p, IMG_H - 1);
    if (c0p > c1p || r0p > r1p) return;

    int tx0 = c0p / TILE, tx1 = c1p / TILE;
    int ty0 = r0p / TILE, ty1 = r1p / TILE;

    const float hx = (TILE/2) * (2.0f / IMG_W);
    const float hy = (TILE/2) * (2.0f / IMG_H);
    float d0 = fabsf(A0)*hx + fabsf(B0)*hy;
    float d1 = fabsf(A1)*hx + fabsf(B1)*hy;
    float d2 = fabsf(A2)*hx + fabsf(B2)*hy;

    for (int ty = ty0; ty <= ty1; ++ty) {
        float cy = 1.0f - ((float)(ty * TILE + TILE/2)) * (2.0f / IMG_H);
        for (int tx = tx0; tx <= tx1; ++tx) {
            float cx = ((float)(tx * TILE + TILE/2)) * (2.0f / IMG_W) - 1.0f;
            float e0 = fmaf(A0, cx, fmaf(B0, cy, C0)) + d0;
            float e1 = fmaf(A1, cx, fmaf(B1, cy, C1)) + d1;
            float e2 = fmaf(A2, cx, fmaf(B2, cy, C2)) + d2;
            if (fminf(fminf(e0, e1), e2) >= -1e-6f) {
                int tile = ty * NTX + tx;
                int pos = atomicAdd(&counts[tile], 1);
                lists[(size_t)tile * F + pos] = f;
            }
        }
    }
}

// (tile, split) blocks: split j processes list entries j, j+RSPLITS, ...
// 16x16 tile, 1 px/thread; faces staged to LDS in rounds.
__global__ __launch_bounds__(256) void raster_binned(
    const float4* __restrict__ fd,
    const int* __restrict__ counts, const int* __restrict__ lists, int F,
    unsigned long long* __restrict__ zbuf)
{
    __shared__ float4 sA[RCHUNK][3];
    __shared__ int    sFi[RCHUNK];

    int b     = blockIdx.x;
    int split = b & (RSPLITS - 1);
    int tile  = b >> 3;                  // log2(RSPLITS)
    int n = counts[tile];
    int total_j = (n > split) ? ((n - split + RSPLITS - 1) / RSPLITS) : 0;
    if (total_j == 0) return;

    int tX = tile & (NTX - 1);
    int tY = tile >> 5;                  // log2(NTX)
    int tid = threadIdx.x;

    int colp = tX * TILE + (tid & 15);
    int rowp = tY * TILE + (tid >> 4);
    float x = ((float)colp + 0.5f) * (2.0f / IMG_W) - 1.0f;
    float y = 1.0f - ((float)rowp + 0.5f) * (2.0f / IMG_H);

    float bz = BIGF;
    int   bi = -1;

    const int* mylist = lists + (size_t)tile * F;

    for (int j0 = 0; j0 < total_j; j0 += RCHUNK) {
        int m = min(RCHUNK, total_j - j0);
        __syncthreads();                 // previous round's LDS fully consumed
        if (tid < m) {
            int e  = split + RSPLITS * (j0 + tid);
            int fi = mylist[e];
            sFi[tid]   = fi;
            sA[tid][0] = fd[3*fi + 0];
            sA[tid][1] = fd[3*fi + 1];
            sA[tid][2] = fd[3*fi + 2];
        }
        __syncthreads();

        for (int s = 0; s < m; ++s) {
            float4 p0 = sA[s][0], p1 = sA[s][1], p2 = sA[s][2];
            int fi = sFi[s];
            float w0 = fmaf(p0.x, x, fmaf(p0.y, y, p0.z));
            float w1 = fmaf(p0.w, x, fmaf(p1.x, y, p1.y));
            float w2 = fmaf(p1.z, x, fmaf(p1.w, y, p2.x));
            float z  = fmaf(p2.y, x, fmaf(p2.z, y, p2.w));
            bool hit = (fminf(fminf(w0, w1), w2) >= 0.0f) && (z > NEARZ);
            if (hit && z < bz) { bz = z; bi = fi; }
        }
    }

    if (bi >= 0) {
        int p = rowp * IMG_W + colp;
        unsigned long long key =
            ((unsigned long long)__float_as_uint(bz) << 32) | (unsigned)bi;
        atomicMin(&zbuf[p], key);
    }
}

__global__ __launch_bounds__(256) void resolve_loss(
    const unsigned long long* __restrict__ zbuf,
    const float* __restrict__ cols,
    const float* __restrict__ imref,
    float* __restrict__ out)
{
    int p = blockIdx.x * 256 + threadIdx.x;
    unsigned long long key = zbuf[p];
    unsigned idx = (unsigned)(key & 0xffffffffull);
    float r = 0.0f, g = 0.0f, bl = 0.0f;
    if (idx != 0xffffffffu) {
        r  = cols[idx*3 + 0];
        g  = cols[idx*3 + 1];
        bl = cols[idx*3 + 2];
    }
    const int HW = IMG_H * IMG_W;
    // image[:, ::-1] reverses the CHANNEL axis
    float d0 = bl - imref[0*HW + p];
    float d1 = g  - imref[1*HW + p];
    float d2 = r  - imref[2*HW + p];
    float loss = fmaf(d0, d0, fmaf(d1, d1, d2*d2));

    #pragma unroll
    for (int off = 32; off > 0; off >>= 1)
        loss += __shfl_down(loss, off, 64);

    __shared__ float wsum[4];
    int wid  = threadIdx.x >> 6;
    int lane = threadIdx.x & 63;
    if (lane == 0) wsum[wid] = loss;
    __syncthreads();
    if (threadIdx.x == 0)
        atomicAdd(out, wsum[0] + wsum[1] + wsum[2] + wsum[3]);
}

// Fallback (small ws): Round-1 monolithic kernel (validated absmax 0).
__global__ __launch_bounds__(256) void raster_loss_mono(
    const float4* __restrict__ fd,
    const float* __restrict__ cols,
    const float* __restrict__ imref,
    float* __restrict__ out, int F)
{
    int p = blockIdx.x * 256 + threadIdx.x;
    int col = p & (IMG_W - 1);
    float x = ((float)col + 0.5f) * (2.0f / IMG_W) - 1.0f;
    float y = 1.0f - ((float)(p >> 9) + 0.5f) * (2.0f / IMG_H);

    float bestz = BIGF;
    int besti = -1;
    for (int f = 0; f < F; ++f) {
        float4 q0 = fd[3*f + 0];
        float4 q1 = fd[3*f + 1];
        float4 q2 = fd[3*f + 2];
        float w0 = fmaf(q0.x, x, fmaf(q0.y, y, q0.z));
        float w1 = fmaf(q0.w, x, fmaf(q1.x, y, q1.y));
        float w2 = fmaf(q1.z, x, fmaf(q1.w, y, q2.x));
        float z  = fmaf(q2.y, x, fmaf(q2.z, y, q2.w));
        bool hit = (w0 >= 0.0f) & (w1 >= 0.0f) & (w2 >= 0.0f) & (z > NEARZ);
        float zm = hit ? z : BIGF;
        if (zm < bestz) { bestz = zm; besti = f; }
    }
    float r = 0.0f, g = 0.0f, bl = 0.0f;
    if (besti >= 0) { r = cols[besti*3]; g = cols[besti*3+1]; bl = cols[besti*3+2]; }
    const int HW = IMG_H * IMG_W;
    float d0 = bl - imref[p], d1 = g - imref[HW+p], d2 = r - imref[2*HW+p];
    float loss = fmaf(d0, d0, fmaf(d1, d1, d2*d2));
    #pragma unroll
    for (int off = 32; off > 0; off >>= 1)
        loss += __shfl_down(loss, off, 64);
    __shared__ float wsum[4];
    int wid = threadIdx.x >> 6, lane = threadIdx.x & 63;
    if (lane == 0) wsum[wid] = loss;
    __syncthreads();
    if (threadIdx.x == 0)
        atomicAdd(out, wsum[0] + wsum[1] + wsum[2] + wsum[3]);
}

extern "C" void kernel_launch(void* const* d_in, const int* in_sizes, int n_in,
                              void* d_out, int out_size, void* d_ws, size_t ws_size,
                              hipStream_t stream)
{
    const float* verts  = (const float*)d_in[0];
    const int*   faces  = (const int*)d_in[1];
    const float* tex    = (const float*)d_in[2];
    const float* campos = (const float*)d_in[3];
    const float* camup  = (const float*)d_in[4];
    const float* imref  = (const float*)d_in[5];
    int F = in_sizes[1] / 3;

    const int P = IMG_H * IMG_W;
    size_t zbytes  = (size_t)P * 8;
    size_t cntB    = (size_t)NTILES * 4;
    size_t listB   = (size_t)NTILES * F * 4;
    size_t fdbytes = (size_t)F * 3 * sizeof(float4);
    size_t cbytes  = (size_t)F * 3 * sizeof(float);
    float* out = (float*)d_out;

    if (ws_size >= zbytes + cntB + listB + fdbytes + cbytes) {
        char* w = (char*)d_ws;
        unsigned long long* zbuf = (unsigned long long*)w;          w += zbytes;
        int*    cnts = (int*)w;                                     w += cntB;
        int*    lst  = (int*)w;                                     w += listB;
        float4* fd   = (float4*)w;                                  w += fdbytes;
        float*  cols = (float*)w;

        hipMemsetAsync(cnts, 0, cntB, stream);
        int pgrid = (F + 255)/256 > 64 ? (F + 255)/256 : 64;  // extra blocks speed zbuf init
        prep_bin<<<pgrid, 256, 0, stream>>>(verts, faces, tex, campos, camup,
                                            fd, cols, zbuf, cnts, lst, out, F);
        raster_binned<<<NTILES * RSPLITS, 256, 0, stream>>>(fd, cnts, lst, F, zbuf);
        resolve_loss<<<P/256, 256, 0, stream>>>(zbuf, cols, imref, out);
    } else {
        float4* fd   = (float4*)d_ws;
        float*  cols = (float*)((char*)d_ws + fdbytes);
        hipMemsetAsync(d_out, 0, sizeof(float), stream);
        prep_bin<<<(F + 255)/256, 256, 0, stream>>>(verts, faces, tex, campos, camup,
                                                    fd, cols, (unsigned long long*)nullptr,
                                                    (int*)nullptr, (int*)nullptr,
                                                    (float*)nullptr, F);
        raster_loss_mono<<<P/256, 256, 0, stream>>>(fd, cols, imref, out, F);
    }
}

// Round 5
// 126.366 us; speedup vs baseline: 1.8074x; 1.8074x over previous
//
#include <hip/hip_runtime.h>

#define IMG_H 512
#define IMG_W 512
#define VIEW_TAN_F 0.57735026918962576451f  // tan(30 deg)
#define NEARZ 0.1f
#define BIGF 1e10f

#define TILE 16
#define NTX (IMG_W / TILE)      // 32 tiles per row
#define NTILES (NTX * NTX)      // 1024 tiles
#define RSPLITS 8               // blocks sharing one tile's face list (strided)
#define RCHUNK 256              // list entries staged to LDS per round

// Per-face data: 3 x float4 = {A0,B0,C0,A1},{B1,C1,A2,B2},{C2,Az,Bz,Cz}
// Edge coefficients premultiplied by sign(area): inside <=> w0,w1,w2 >= 0.
// z = Az*x + Bz*y + Cz (affine; division by area folded into coefficients).

// Per-face setup + zbuf/out init. NO binning here (R4 lesson: serial per-face
// tile loops are latency death; binning is tile-parallel in bin_tiles).
__global__ void prep_faces(const float* __restrict__ verts,
                           const int* __restrict__ faces,
                           const float* __restrict__ tex,
                           const float* __restrict__ campos,
                           const float* __restrict__ camup,
                           float4* __restrict__ fd,
                           float* __restrict__ cols,
                           unsigned long long* __restrict__ zbuf,
                           float* __restrict__ out,
                           int F)
{
    int gid = blockIdx.x * blockDim.x + threadIdx.x;

    if (gid == 0 && out) out[0] = 0.0f;      // d_out poisoned 0xAA each call

    if (zbuf) {
        const int P = IMG_H * IMG_W;
        for (int i = gid; i < P; i += gridDim.x * blockDim.x)
            zbuf[i] = ~0ull;
    }

    int f = gid;
    if (f >= F) return;

    float ex = campos[0], ey = campos[1], ez = campos[2];
    float ux = camup[0], uy = camup[1], uz = camup[2];
    float zxv = -ex, zyv = -ey, zzv = -ez;
    float inv = 1.0f / (sqrtf(zxv*zxv + zyv*zyv + zzv*zzv) + 1e-12f);
    zxv *= inv; zyv *= inv; zzv *= inv;
    inv = 1.0f / (sqrtf(ux*ux + uy*uy + uz*uz) + 1e-12f);
    ux *= inv; uy *= inv; uz *= inv;
    float xxv = uy*zzv - uz*zyv;
    float xyv = uz*zxv - ux*zzv;
    float xzv = ux*zyv - uy*zxv;
    inv = 1.0f / (sqrtf(xxv*xxv + xyv*xyv + xzv*xzv) + 1e-12f);
    xxv *= inv; xyv *= inv; xzv *= inv;
    float yxv = zyv*xzv - zzv*xyv;
    float yyv = zzv*xxv - zxv*xzv;
    float yzv = zxv*xyv - zyv*xxv;

    float px_[3], py_[3], pz_[3];
    #pragma unroll
    for (int k = 0; k < 3; ++k) {
        int vi = faces[f*3 + k];
        float vx = verts[vi*3+0] - ex;
        float vy = verts[vi*3+1] - ey;
        float vz = verts[vi*3+2] - ez;
        float cx = xxv*vx + xyv*vy + xzv*vz;
        float cy = yxv*vx + yyv*vy + yzv*vz;
        float cz = zxv*vx + zyv*vy + zzv*vz;
        float denom = cz * VIEW_TAN_F + 1e-12f;
        px_[k] = cx / denom;
        py_[k] = cy / denom;
        pz_[k] = cz;
    }
    float x0 = px_[0], y0 = py_[0];
    float x1 = px_[1], y1 = py_[1];
    float x2 = px_[2], y2 = py_[2];
    float area = (x1-x0)*(y2-y0) - (y1-y0)*(x2-x0);
    bool valid = fabsf(area) > 1e-8f;
    float safe = valid ? area : 1.0f;
    float s = (area > 0.0f) ? 1.0f : -1.0f;

    float A0 = -(y2-y1), B0 = (x2-x1), C0 = (y2-y1)*x1 - (x2-x1)*y1;
    float A1 = -(y0-y2), B1 = (x0-x2), C1 = (y0-y2)*x2 - (x0-x2)*y2;
    float A2 = -(y1-y0), B2 = (x1-x0), C2 = (y1-y0)*x0 - (x1-x0)*y0;

    float invs = 1.0f / safe;
    float Az = (A0*pz_[0] + A1*pz_[1] + A2*pz_[2]) * invs;
    float Bz = (B0*pz_[0] + B1*pz_[1] + B2*pz_[2]) * invs;
    float Cz = (C0*pz_[0] + C1*pz_[1] + C2*pz_[2]) * invs;

    A0 *= s; B0 *= s; C0 *= s;
    A1 *= s; B1 *= s; C1 *= s;
    A2 *= s; B2 *= s; C2 *= s;

    if (!valid) {
        A0 = B0 = A1 = B1 = A2 = B2 = 0.0f;
        C0 = C1 = C2 = -1.0f;   // always fails inside + tile tests
        Az = Bz = 0.0f; Cz = 0.0f;
    }

    fd[f*3+0] = make_float4(A0, B0, C0, A1);
    fd[f*3+1] = make_float4(B1, C1, A2, B2);
    fd[f*3+2] = make_float4(C2, Az, Bz, Cz);

    float c0 = 0.0f, c1 = 0.0f, c2 = 0.0f;
    #pragma unroll
    for (int t = 0; t < 8; ++t) {
        c0 += tex[f*24 + t*3 + 0];
        c1 += tex[f*24 + t*3 + 1];
        c2 += tex[f*24 + t*3 + 2];
    }
    cols[f*3+0] = c0 * 0.125f;
    cols[f*3+1] = c1 * 0.125f;
    cols[f*3+2] = c2 * 0.125f;
}

// One block per 16x16 tile (1024 blocks, ~4/CU): conservative dilated-edge
// test vs tile rect, ballot-compact surviving face ids into the tile's list.
__global__ __launch_bounds__(256) void bin_tiles(
    const float4* __restrict__ fd, int F,
    int* __restrict__ counts, int* __restrict__ lists)
{
    __shared__ int sCnt;
    int tile = blockIdx.x;
    int tX = tile & (NTX - 1);
    int tY = tile >> 5;                  // log2(NTX)
    int tid  = threadIdx.x;
    int lane = tid & 63;

    float cx = ((float)(tX * TILE + TILE/2)) * (2.0f / IMG_W) - 1.0f;
    float cy = 1.0f - ((float)(tY * TILE + TILE/2)) * (2.0f / IMG_H);
    const float hx = (TILE/2) * (2.0f / IMG_W);
    const float hy = (TILE/2) * (2.0f / IMG_H);

    if (tid == 0) sCnt = 0;
    __syncthreads();

    int* mylist = lists + (size_t)tile * F;
    for (int c0f = 0; c0f < F; c0f += 256) {
        int f = c0f + tid;
        bool pass = false;
        if (f < F) {
            float4 q0 = fd[3*f + 0];
            float4 q1 = fd[3*f + 1];
            float4 q2 = fd[3*f + 2];
            float e0 = fmaf(q0.x, cx, fmaf(q0.y, cy, q0.z)) + fabsf(q0.x)*hx + fabsf(q0.y)*hy;
            float e1 = fmaf(q0.w, cx, fmaf(q1.x, cy, q1.y)) + fabsf(q0.w)*hx + fabsf(q1.x)*hy;
            float e2 = fmaf(q1.z, cx, fmaf(q1.w, cy, q2.x)) + fabsf(q1.z)*hx + fabsf(q1.w)*hy;
            pass = fminf(fminf(e0, e1), e2) >= -1e-6f;
        }
        unsigned long long m = __ballot(pass);
        int wbase = 0;
        if (lane == 0 && m) wbase = atomicAdd(&sCnt, __popcll(m));
        wbase = __shfl(wbase, 0, 64);
        if (pass) {
            int pos = wbase + __popcll(m & ((1ull << lane) - 1ull));
            mylist[pos] = f;
        }
    }
    __syncthreads();
    if (tid == 0) counts[tile] = sCnt;
}

// (tile, split) blocks: split j processes list entries j, j+RSPLITS, ...
// 16x16 tile, 1 px/thread; faces staged to LDS in rounds.
__global__ __launch_bounds__(256) void raster_binned(
    const float4* __restrict__ fd,
    const int* __restrict__ counts, const int* __restrict__ lists, int F,
    unsigned long long* __restrict__ zbuf)
{
    __shared__ float4 sA[RCHUNK][3];
    __shared__ int    sFi[RCHUNK];

    int b     = blockIdx.x;
    int split = b & (RSPLITS - 1);
    int tile  = b >> 3;                  // log2(RSPLITS)
    int n = counts[tile];
    int total_j = (n > split) ? ((n - split + RSPLITS - 1) / RSPLITS) : 0;
    if (total_j == 0) return;

    int tX = tile & (NTX - 1);
    int tY = tile >> 5;                  // log2(NTX)
    int tid = threadIdx.x;

    int colp = tX * TILE + (tid & 15);
    int rowp = tY * TILE + (tid >> 4);
    float x = ((float)colp + 0.5f) * (2.0f / IMG_W) - 1.0f;
    float y = 1.0f - ((float)rowp + 0.5f) * (2.0f / IMG_H);

    float bz = BIGF;
    int   bi = -1;

    const int* mylist = lists + (size_t)tile * F;

    for (int j0 = 0; j0 < total_j; j0 += RCHUNK) {
        int m = min(RCHUNK, total_j - j0);
        __syncthreads();                 // previous round's LDS fully consumed
        if (tid < m) {
            int e  = split + RSPLITS * (j0 + tid);
            int fi = mylist[e];
            sFi[tid]   = fi;
            sA[tid][0] = fd[3*fi + 0];
            sA[tid][1] = fd[3*fi + 1];
            sA[tid][2] = fd[3*fi + 2];
        }
        __syncthreads();

        for (int s = 0; s < m; ++s) {
            float4 p0 = sA[s][0], p1 = sA[s][1], p2 = sA[s][2];
            int fi = sFi[s];
            float w0 = fmaf(p0.x, x, fmaf(p0.y, y, p0.z));
            float w1 = fmaf(p0.w, x, fmaf(p1.x, y, p1.y));
            float w2 = fmaf(p1.z, x, fmaf(p1.w, y, p2.x));
            float z  = fmaf(p2.y, x, fmaf(p2.z, y, p2.w));
            bool hit = (fminf(fminf(w0, w1), w2) >= 0.0f) && (z > NEARZ);
            if (hit && z < bz) { bz = z; bi = fi; }
        }
    }

    if (bi >= 0) {
        int p = rowp * IMG_W + colp;
        unsigned long long key =
            ((unsigned long long)__float_as_uint(bz) << 32) | (unsigned)bi;
        atomicMin(&zbuf[p], key);
    }
}

__global__ __launch_bounds__(256) void resolve_loss(
    const unsigned long long* __restrict__ zbuf,
    const float* __restrict__ cols,
    const float* __restrict__ imref,
    float* __restrict__ out)
{
    int p = blockIdx.x * 256 + threadIdx.x;
    unsigned long long key = zbuf[p];
    unsigned idx = (unsigned)(key & 0xffffffffull);
    float r = 0.0f, g = 0.0f, bl = 0.0f;
    if (idx != 0xffffffffu) {
        r  = cols[idx*3 + 0];
        g  = cols[idx*3 + 1];
        bl = cols[idx*3 + 2];
    }
    const int HW = IMG_H * IMG_W;
    // image[:, ::-1] reverses the CHANNEL axis
    float d0 = bl - imref[0*HW + p];
    float d1 = g  - imref[1*HW + p];
    float d2 = r  - imref[2*HW + p];
    float loss = fmaf(d0, d0, fmaf(d1, d1, d2*d2));

    #pragma unroll
    for (int off = 32; off > 0; off >>= 1)
        loss += __shfl_down(loss, off, 64);

    __shared__ float wsum[4];
    int wid  = threadIdx.x >> 6;
    int lane = threadIdx.x & 63;
    if (lane == 0) wsum[wid] = loss;
    __syncthreads();
    if (threadIdx.x == 0)
        atomicAdd(out, wsum[0] + wsum[1] + wsum[2] + wsum[3]);
}

// Fallback (small ws): Round-1 monolithic kernel (validated absmax 0).
__global__ __launch_bounds__(256) void raster_loss_mono(
    const float4* __restrict__ fd,
    const float* __restrict__ cols,
    const float* __restrict__ imref,
    float* __restrict__ out, int F)
{
    int p = blockIdx.x * 256 + threadIdx.x;
    int col = p & (IMG_W - 1);
    float x = ((float)col + 0.5f) * (2.0f / IMG_W) - 1.0f;
    float y = 1.0f - ((float)(p >> 9) + 0.5f) * (2.0f / IMG_H);

    float bestz = BIGF;
    int besti = -1;
    for (int f = 0; f < F; ++f) {
        float4 q0 = fd[3*f + 0];
        float4 q1 = fd[3*f + 1];
        float4 q2 = fd[3*f + 2];
        float w0 = fmaf(q0.x, x, fmaf(q0.y, y, q0.z));
        float w1 = fmaf(q0.w, x, fmaf(q1.x, y, q1.y));
        float w2 = fmaf(q1.z, x, fmaf(q1.w, y, q2.x));
        float z  = fmaf(q2.y, x, fmaf(q2.z, y, q2.w));
        bool hit = (w0 >= 0.0f) & (w1 >= 0.0f) & (w2 >= 0.0f) & (z > NEARZ);
        float zm = hit ? z : BIGF;
        if (zm < bestz) { bestz = zm; besti = f; }
    }
    float r = 0.0f, g = 0.0f, bl = 0.0f;
    if (besti >= 0) { r = cols[besti*3]; g = cols[besti*3+1]; bl = cols[besti*3+2]; }
    const int HW = IMG_H * IMG_W;
    float d0 = bl - imref[p], d1 = g - imref[HW+p], d2 = r - imref[2*HW+p];
    float loss = fmaf(d0, d0, fmaf(d1, d1, d2*d2));
    #pragma unroll
    for (int off = 32; off > 0; off >>= 1)
        loss += __shfl_down(loss, off, 64);
    __shared__ float wsum[4];
    int wid = threadIdx.x >> 6, lane = threadIdx.x & 63;
    if (lane == 0) wsum[wid] = loss;
    __syncthreads();
    if (threadIdx.x == 0)
        atomicAdd(out, wsum[0] + wsum[1] + wsum[2] + wsum[3]);
}

extern "C" void kernel_launch(void* const* d_in, const int* in_sizes, int n_in,
                              void* d_out, int out_size, void* d_ws, size_t ws_size,
                              hipStream_t stream)
{
    const float* verts  = (const float*)d_in[0];
    const int*   faces  = (const int*)d_in[1];
    const float* tex    = (const float*)d_in[2];
    const float* campos = (const float*)d_in[3];
    const float* camup  = (const float*)d_in[4];
    const float* imref  = (const float*)d_in[5];
    int F = in_sizes[1] / 3;

    const int P = IMG_H * IMG_W;
    size_t zbytes  = (size_t)P * 8;
    size_t cntB    = (size_t)NTILES * 4;
    size_t listB   = (size_t)NTILES * F * 4;
    size_t fdbytes = (size_t)F * 3 * sizeof(float4);
    size_t cbytes  = (size_t)F * 3 * sizeof(float);
    float* out = (float*)d_out;

    if (ws_size >= zbytes + cntB + listB + fdbytes + cbytes) {
        char* w = (char*)d_ws;
        unsigned long long* zbuf = (unsigned long long*)w;          w += zbytes;
        int*    cnts = (int*)w;                                     w += cntB;
        int*    lst  = (int*)w;                                     w += listB;
        float4* fd   = (float4*)w;                                  w += fdbytes;
        float*  cols = (float*)w;

        int pgrid = (F + 255)/256 > 128 ? (F + 255)/256 : 128;  // extra blocks speed zbuf init
        prep_faces<<<pgrid, 256, 0, stream>>>(verts, faces, tex, campos, camup,
                                              fd, cols, zbuf, out, F);
        bin_tiles<<<NTILES, 256, 0, stream>>>(fd, F, cnts, lst);
        raster_binned<<<NTILES * RSPLITS, 256, 0, stream>>>(fd, cnts, lst, F, zbuf);
        resolve_loss<<<P/256, 256, 0, stream>>>(zbuf, cols, imref, out);
    } else {
        float4* fd   = (float4*)d_ws;
        float*  cols = (float*)((char*)d_ws + fdbytes);
        hipMemsetAsync(d_out, 0, sizeof(float), stream);
        prep_faces<<<(F + 255)/256, 256, 0, stream>>>(verts, faces, tex, campos, camup,
                                                      fd, cols, (unsigned long long*)nullptr,
                                                      (float*)nullptr, F);
        raster_loss_mono<<<P/256, 256, 0, stream>>>(fd, cols, imref, out, F);
    }
}